// Round 6
// baseline (211.534 us; speedup 1.0000x reference)
//
#include <hip/hip_runtime.h>

typedef unsigned short u16;
typedef __bf16 bf8 __attribute__((ext_vector_type(8)));
typedef __bf16 bf2 __attribute__((ext_vector_type(2)));
typedef float f4 __attribute__((ext_vector_type(4)));

typedef __attribute__((address_space(1))) const unsigned int gas_u32;
typedef __attribute__((address_space(3))) unsigned int las_u32;
#define ASYNC16(g, l) __builtin_amdgcn_global_load_lds((gas_u32*)(g), (las_u32*)(l), 16, 0, 0)

__device__ __forceinline__ u16 f2bf(float f) {
    union { float f; unsigned int u; } v; v.f = f;
    return (u16)((v.u + 0x7fffu + ((v.u >> 16) & 1u)) >> 16);
}

// pack two f32 -> bf16x2 word via HW cvt (compiler emits v_cvt_pk_bf16_f32, RNE).
__device__ __forceinline__ unsigned pkbf(float lo, float hi) {
    union { bf2 v; unsigned u; } t;
    t.v[0] = (__bf16)lo;
    t.v[1] = (__bf16)hi;
    return t.u;
}

__device__ __forceinline__ float fexp2(float x) {
#if __has_builtin(__builtin_amdgcn_exp2f)
  return __builtin_amdgcn_exp2f(x);
#else
  return __expf(x * 0.69314718056f);
#endif
}

// ---------------- fp32 -> bf16 conversion of inputs + weights ----------------
__global__ __launch_bounds__(256) void cvt_all(
    const float* __restrict__ k_, const float* __restrict__ q_, const float* __restrict__ v_,
    const float* __restrict__ wq, const float* __restrict__ wk, const float* __restrict__ wv,
    const float* __restrict__ wo, u16* __restrict__ ws) {
  size_t e = ((size_t)blockIdx.x * 256 + threadIdx.x) * 8;
  const float* src;
  if      (e <  4194304) src = k_ + e;
  else if (e <  8388608) src = q_ + (e - 4194304);
  else if (e < 12582912) src = v_ + (e - 8388608);
  else if (e < 13631488) src = wq + (e - 12582912);
  else if (e < 14680064) src = wk + (e - 13631488);
  else if (e < 15728640) src = wv + (e - 14680064);
  else                   src = wo + (e - 15728640);
  float4 f0 = ((const float4*)src)[0];
  float4 f1 = ((const float4*)src)[1];
  uint4 o;
  o.x = (unsigned)f2bf(f0.x) | ((unsigned)f2bf(f0.y) << 16);
  o.y = (unsigned)f2bf(f0.z) | ((unsigned)f2bf(f0.w) << 16);
  o.z = (unsigned)f2bf(f1.x) | ((unsigned)f2bf(f1.y) << 16);
  o.w = (unsigned)f2bf(f1.z) | ((unsigned)f2bf(f1.w) << 16);
  *(uint4*)(ws + e) = o;
}

// ---------------- GEMM tile v2: BK=64 (half the barriers), chunk-XOR swizzled LDS ----------------
// C = scale * (A[M,K] @ B[N,K]^T), K=1024. BM x 128 tile, 256 threads = 2x2 waves.
// LDS row stride 64 elem (128 B); 16B chunk c stored at c^(row&7) (swizzle applied on the
// GLOBAL address per global_load_lds's linear-LDS requirement). b128 frag reads are 2-way.
template<int BM, bool FINAL>
__device__ __forceinline__ void gemm_tile(const u16* __restrict__ A, const u16* __restrict__ Bm,
                                          u16* __restrict__ Cb, float* __restrict__ Cf,
                                          const float* __restrict__ bias, float scale,
                                          int bm, int bn, int ldc) {
  __shared__ u16 As[BM*64];
  __shared__ u16 Bs[128*64];
  const int tid = threadIdx.x;
  const int wave = tid >> 6, lane = tid & 63;
  const int wm = wave >> 1, wn = wave & 1;
  const int quad = lane >> 4, l16 = lane & 15;
  const int MI = BM / 32;

  f4 acc[MI][4];
  const f4 zz = {0.f, 0.f, 0.f, 0.f};
  #pragma unroll
  for (int i = 0; i < MI; i++)
    #pragma unroll
    for (int j = 0; j < 4; j++) acc[i][j] = zz;

  // staging: thread t covers row kr=t>>3 (+p*32), swizzled chunk cs
  const int kr = tid >> 3;
  const int cs = (tid & 7) ^ (kr & 7);
  const u16* ga = A  + (size_t)(bm*BM  + kr)*1024 + cs*8;
  const u16* gb = Bm + (size_t)(bn*128 + kr)*1024 + cs*8;
  u16* la = As + tid*8;
  u16* lb = Bs + tid*8;

  for (int kt = 0; kt < 1024; kt += 64) {
    #pragma unroll
    for (int p = 0; p < BM/32; p++) ASYNC16(ga + (size_t)(p*32)*1024 + kt, la + p*2048);
    #pragma unroll
    for (int p = 0; p < 4; p++)     ASYNC16(gb + (size_t)(p*32)*1024 + kt, lb + p*2048);
    __syncthreads();               // drains DMA -> tile visible
    #pragma unroll
    for (int kk = 0; kk < 2; kk++) {
      bf8 af[MI];
      #pragma unroll
      for (int mi = 0; mi < MI; mi++)
        af[mi] = *(const bf8*)(As + (wm*(BM/2) + mi*16 + l16)*64 + (((kk*4 + quad) ^ (l16 & 7))*8));
      #pragma unroll
      for (int ni = 0; ni < 4; ni++) {
        bf8 bfr = *(const bf8*)(Bs + (wn*64 + ni*16 + l16)*64 + (((kk*4 + quad) ^ (l16 & 7))*8));
        #pragma unroll
        for (int mi = 0; mi < MI; mi++)
          acc[mi][ni] = __builtin_amdgcn_mfma_f32_16x16x32_bf16(af[mi], bfr, acc[mi][ni], 0, 0, 0);
      }
    }
    __syncthreads();               // all frag reads done before next DMA overwrites
  }

  #pragma unroll
  for (int mi = 0; mi < MI; mi++)
    #pragma unroll
    for (int ni = 0; ni < 4; ni++) {
      const int col = bn*128 + wn*64 + ni*16 + l16;
      #pragma unroll
      for (int r = 0; r < 4; r++) {
        const int row = bm*BM + wm*(BM/2) + mi*16 + quad*4 + r;
        if (FINAL) Cf[(size_t)row*ldc + col] = acc[mi][ni][r] + bias[col];
        else       Cb[(size_t)row*ldc + col] = f2bf(acc[mi][ni][r] * scale);
      }
    }
}

// Q pre-scaled by 0.125*log2(e) so flash_attn uses raw exp2.
#define QSCALE 0.180336880f

// Grid (32,8,3): x = M-tile -> XCD = bm%8, so A-panels are XCD-resident and W streams
// through each XCD's L2 (2 MB < 4 MB). z=2 computes V^T = Wv@xv^T (coalesced transposed out).
__global__ __launch_bounds__(256, 3) void gemm_qkv(
    const u16* __restrict__ xq, const u16* __restrict__ xk, const u16* __restrict__ xv,
    const u16* __restrict__ wq, const u16* __restrict__ wk, const u16* __restrict__ wv,
    u16* __restrict__ Qo, u16* __restrict__ Ko, u16* __restrict__ Vto) {
  if (blockIdx.z == 0)
    gemm_tile<128,false>(xq, wq, Qo, nullptr, nullptr, QSCALE, blockIdx.x, blockIdx.y, 1024);
  else if (blockIdx.z == 1)
    gemm_tile<128,false>(xk, wk, Ko, nullptr, nullptr, 1.0f, blockIdx.x, blockIdx.y, 1024);
  else
    gemm_tile<128,false>(wv, xv, Vto, nullptr, nullptr, 1.0f, blockIdx.y, blockIdx.x, 4096);
}

// Grid (64,8): x = M-tile (64 rows) -> XCD-aligned ctx panels.
__global__ __launch_bounds__(256, 2) void gemm_out(
    const u16* __restrict__ ctx, const u16* __restrict__ wo,
    const float* __restrict__ bias, float* __restrict__ out) {
  gemm_tile<64,true>(ctx, wo, nullptr, out, bias, 1.0f, blockIdx.x, blockIdx.y, 1024);
}

// ---------------- flash attention v8: v7 + double-buffered K/V, counted vmcnt (T3/T4) --------
// Grid (16,32,2): x = h -> XCD = h%8: each XCD caches 4 K/V slabs (2 MB) across its 32 qt blocks.
// v6: permuted-key QK^T makes P lane-local (frag f reads K row (l16>>2)*8+f*4+(l16&3)) -> P
//     feeds PV's B-operand directly, zero LDS traffic.  v7: setprio(1) around MFMA clusters.
// v8: kill the per-tile vmcnt(0) drain (m233: stage+drain+barrier is ~72% of a 2-phase loop's
// critical path). 2 LDS buffers of (K 16KB + V 16KB); per tile: issue 8 DMA loads for t+1 into
// buf[t+1], s_waitcnt vmcnt(8) (waits only t's loads, issued one full iteration ago), barrier,
// compute buf[t], lgkmcnt(0)+barrier (reads complete before next overwrite). 2 barriers/tile
// as before, but the wait is ~free in steady state. Cost: LDS 64KB -> 2 blocks/CU.
__global__ __launch_bounds__(256, 2) void flash_attn(
    const u16* __restrict__ Qg, const u16* __restrict__ Kg,
    const u16* __restrict__ Vtg, u16* __restrict__ ctx) {
  __shared__ uint4 smem4[4096];              // 65536 B = 2 x (K [128][64] + V^T [64][128]) bf16
  u16* S = (u16*)smem4;                      // buf b at elem b*16384: K at +0, V^T at +8192
  float* Of = (float*)smem4;                 // epilogue overlay: 2 x [64][68] f32 = 34816 B
  float* Lf = (float*)smem4 + 2*64*68;       // 128 f32 -> 35328 B total (fits under 65536)

  const int tid = threadIdx.x;
  const int wave = tid >> 6, lane = tid & 63;
  const int quad = lane >> 4, l16 = lane & 15;
  const int wq = wave >> 1, wk = wave & 1;
  const int h = blockIdx.x, qt = blockIdx.y, b = blockIdx.z;

  // Q B-frags (B[n=qrow=l16][k=dim=quad*8+j]); one-time global load
  bf8 qf[2][2];
  {
    const u16* qp = Qg + (size_t)(b*2048 + qt*64 + wq*32)*1024 + h*64;
    #pragma unroll
    for (int qs = 0; qs < 2; qs++)
      #pragma unroll
      for (int kc = 0; kc < 2; kc++)
        qf[qs][kc] = *(const bf8*)(qp + (size_t)(qs*16 + l16)*1024 + kc*32 + quad*8);
  }

  const f4 zz = {0.f, 0.f, 0.f, 0.f};
  f4 ot[4][2];                 // O^T acc: [d-sub][q-sub], elem (row=d=quad*4+r, col=qrow=l16)
  float lrow[2] = {0.f, 0.f};  // per-lane denominator partial
  #pragma unroll
  for (int ds = 0; ds < 4; ds++)
    #pragma unroll
    for (int qs = 0; qs < 2; qs++) ot[ds][qs] = zz;

  // staging bases (global side carries the XOR chunk-swizzle; LDS side linear)
  const int kr = tid >> 3;
  const u16* kga = Kg + (size_t)(b*2048 + kr)*1024 + h*64 + ((tid & 7) ^ (kr & 7))*8;
  const int vd = tid >> 4;
  const u16* vga = Vtg + (size_t)(h*64 + vd)*4096 + b*2048 + (((tid & 15) ^ vd))*8;

  // permuted K-row bases for the two QK frags (f=0,1): within a 32-key block,
  // frag f, lane (quad,l16) reads key-row (l16>>2)*8 + f*4 + (l16&3).
  const int prow0 = ((l16 >> 2) << 3) + (l16 & 3);      // f=0
  const int prow1 = prow0 + 4;                           // f=1

  // prologue: issue tile 0 into buf 0 (8 DMA loads/wave)
  #pragma unroll
  for (int p = 0; p < 4; p++) ASYNC16(kga + (size_t)(p*32)*1024, S + tid*8 + p*2048);
  #pragma unroll
  for (int p = 0; p < 4; p++) ASYNC16(vga + (size_t)(p*16)*4096, S + 8192 + tid*8 + p*2048);

  for (int t = 0; t < 16; t++) {
    u16* Ks = S + (t & 1)*16384;
    u16* Vt = Ks + 8192;
    if (t < 15) {
      // issue tile t+1 into the other buffer (read-complete since last iter's tail barrier)
      u16* kd = S + ((t+1) & 1)*16384 + tid*8;
      const int kv1 = (t+1)*128;
      #pragma unroll
      for (int p = 0; p < 4; p++) ASYNC16(kga + (size_t)(kv1 + p*32)*1024, kd + p*2048);
      #pragma unroll
      for (int p = 0; p < 4; p++) ASYNC16(vga + (size_t)(p*16)*4096 + kv1, kd + 8192 + p*2048);
      asm volatile("s_waitcnt vmcnt(8)" ::: "memory");   // tile t's 8 loads landed
    } else {
      asm volatile("s_waitcnt vmcnt(0)" ::: "memory");   // last tile: full drain
    }
    __builtin_amdgcn_sched_barrier(0);
    __builtin_amdgcn_s_barrier();    // tile t visible to all waves

    #pragma unroll
    for (int kb = 0; kb < 2; kb++) {
      // --- S^T = K @ Q^T, keys permuted so output is PV-operand-local ---
      f4 st[2][2];                 // [f][qs]: scores for keys quad*8 + f*4 + r
      #pragma unroll
      for (int f = 0; f < 2; f++)
        #pragma unroll
        for (int qs = 0; qs < 2; qs++) st[f][qs] = zz;
      __builtin_amdgcn_s_setprio(1);
      #pragma unroll
      for (int f = 0; f < 2; f++) {
        const int row = wk*64 + kb*32 + (f ? prow1 : prow0);
        #pragma unroll
        for (int kc = 0; kc < 2; kc++) {
          bf8 kf = *(const bf8*)(Ks + row*64 + (((kc*4 + quad) ^ (row & 7))*8));
          #pragma unroll
          for (int qs = 0; qs < 2; qs++)
            st[f][qs] = __builtin_amdgcn_mfma_f32_16x16x32_bf16(kf, qf[qs][kc], st[f][qs], 0, 0, 0);
        }
      }
      __builtin_amdgcn_s_setprio(0);
      // --- exp2, per-lane row-sum, cvt_pk straight into the PV B-frag ---
      bf8 pf[2];
      #pragma unroll
      for (int qs = 0; qs < 2; qs++) {
        float p0 = fexp2(st[0][qs][0]), p1 = fexp2(st[0][qs][1]);
        float p2 = fexp2(st[0][qs][2]), p3 = fexp2(st[0][qs][3]);
        float p4 = fexp2(st[1][qs][0]), p5 = fexp2(st[1][qs][1]);
        float p6 = fexp2(st[1][qs][2]), p7 = fexp2(st[1][qs][3]);
        lrow[qs] += ((p0 + p1) + (p2 + p3)) + ((p4 + p5) + (p6 + p7));
        union { uint4 u; bf8 v; } pu;
        pu.u.x = pkbf(p0, p1);     // keys quad*8 + 0,1
        pu.u.y = pkbf(p2, p3);     // keys quad*8 + 2,3
        pu.u.z = pkbf(p4, p5);     // keys quad*8 + 4,5
        pu.u.w = pkbf(p6, p7);     // keys quad*8 + 6,7
        pf[qs] = pu.v;
      }
      // --- O^T += V^T-frag @ P ---
      __builtin_amdgcn_s_setprio(1);
      #pragma unroll
      for (int ds = 0; ds < 4; ds++) {
        const int d = ds*16 + l16;
        bf8 vf = *(const bf8*)(Vt + d*128 + (((wk*8 + kb*4 + quad) ^ l16)*8));
        #pragma unroll
        for (int qs = 0; qs < 2; qs++)
          ot[ds][qs] = __builtin_amdgcn_mfma_f32_16x16x32_bf16(vf, pf[qs], ot[ds][qs], 0, 0, 0);
      }
      __builtin_amdgcn_s_setprio(0);
    }

    // reads of buf[t] complete (in data, not just issue) before next iter overwrites it
    asm volatile("s_waitcnt lgkmcnt(0)" ::: "memory");
    __builtin_amdgcn_s_barrier();
  }

  // ---------------- epilogue: reduce key-stripes, transpose, normalize, store ----------------
  __syncthreads();                 // everyone done with Ks/Vt -> safe to overlay
  #pragma unroll
  for (int qs = 0; qs < 2; qs++) {
    lrow[qs] += __shfl_xor(lrow[qs], 16);
    lrow[qs] += __shfl_xor(lrow[qs], 32);
  }
  float* Ofw = Of + wk*(64*68);
  #pragma unroll
  for (int ds = 0; ds < 4; ds++)
    #pragma unroll
    for (int qs = 0; qs < 2; qs++)
      #pragma unroll
      for (int r = 0; r < 4; r++)
        Ofw[(wq*32 + qs*16 + l16)*68 + ds*16 + quad*4 + r] = ot[ds][qs][r];
  if (quad == 0) {
    Lf[wk*64 + wq*32 + l16]      = lrow[0];
    Lf[wk*64 + wq*32 + 16 + l16] = lrow[1];
  }
  __syncthreads();
  {
    const int qr = tid >> 2, dp = (tid & 3)*16;
    const float inv = 1.f / (Lf[qr] + Lf[64 + qr]);
    const float* o0 = Of + qr*68 + dp;
    const float* o1 = o0 + 64*68;
    unsigned ow[8];
    #pragma unroll
    for (int i = 0; i < 8; i++)
      ow[i] = pkbf((o0[2*i] + o1[2*i]) * inv, (o0[2*i+1] + o1[2*i+1]) * inv);
    u16* cp = ctx + (size_t)(b*2048 + qt*64 + qr)*1024 + h*64 + dp;
    *(uint4*)cp       = *(uint4*)&ow[0];
    *(uint4*)(cp + 8) = *(uint4*)&ow[4];
  }
}

extern "C" void kernel_launch(void* const* d_in, const int* in_sizes, int n_in,
                              void* d_out, int out_size, void* d_ws, size_t ws_size,
                              hipStream_t stream) {
  const float* key_  = (const float*)d_in[0];
  const float* query = (const float*)d_in[1];
  const float* value = (const float*)d_in[2];
  const float* Wq = (const float*)d_in[3];
  const float* Wk = (const float*)d_in[4];
  const float* Wv = (const float*)d_in[5];
  const float* Wo = (const float*)d_in[6];
  const float* bo = (const float*)d_in[7];
  float* out = (float*)d_out;

  u16* ws  = (u16*)d_ws;                 // needs 67.1 MB of workspace
  u16* xkb = ws;
  u16* xqb = ws + 4194304;
  u16* xvb = ws + 8388608;
  u16* Wqb = ws + 12582912;
  u16* Wkb = ws + 13631488;
  u16* Wvb = ws + 14680064;
  u16* Wob = ws + 15728640;
  u16* Qb  = ws + 16777216;              // Q (pre-scaled by 0.125*log2e) [4096,1024] bf16
  u16* Kb  = ws + 20971520;              // K [4096,1024] bf16
  u16* Vtb = ws + 25165824;              // V^T [1024,4096] bf16
  u16* Cb  = ws + 29360128;              // attention context [4096,1024] bf16

  cvt_all<<<8192, 256, 0, stream>>>(key_, query, value, Wq, Wk, Wv, Wo, ws);
  gemm_qkv<<<dim3(32, 8, 3), 256, 0, stream>>>(xqb, xkb, xvb, Wqb, Wkb, Wvb, Qb, Kb, Vtb);
  flash_attn<<<dim3(16, 32, 2), 256, 0, stream>>>(Qb, Kb, Vtb, Cb);
  gemm_out<<<dim3(64, 8), 256, 0, stream>>>(Cb, Wob, bo, out);
}

// Round 7
// 193.865 us; speedup vs baseline: 1.0911x; 1.0911x over previous
//
#include <hip/hip_runtime.h>

typedef unsigned short u16;
typedef __bf16 bf8 __attribute__((ext_vector_type(8)));
typedef __bf16 bf2 __attribute__((ext_vector_type(2)));
typedef float f4 __attribute__((ext_vector_type(4)));

typedef __attribute__((address_space(1))) const unsigned int gas_u32;
typedef __attribute__((address_space(3))) unsigned int las_u32;
#define ASYNC16(g, l) __builtin_amdgcn_global_load_lds((gas_u32*)(g), (las_u32*)(l), 16, 0, 0)

__device__ __forceinline__ u16 f2bf(float f) {
    union { float f; unsigned int u; } v; v.f = f;
    return (u16)((v.u + 0x7fffu + ((v.u >> 16) & 1u)) >> 16);
}

// pack two f32 -> bf16x2 word via HW cvt (compiler emits v_cvt_pk_bf16_f32, RNE).
__device__ __forceinline__ unsigned pkbf(float lo, float hi) {
    union { bf2 v; unsigned u; } t;
    t.v[0] = (__bf16)lo;
    t.v[1] = (__bf16)hi;
    return t.u;
}

__device__ __forceinline__ float fexp2(float x) {
#if __has_builtin(__builtin_amdgcn_exp2f)
  return __builtin_amdgcn_exp2f(x);
#else
  return __expf(x * 0.69314718056f);
#endif
}

// ---------------- fp32 -> bf16 conversion of inputs + weights ----------------
__global__ __launch_bounds__(256) void cvt_all(
    const float* __restrict__ k_, const float* __restrict__ q_, const float* __restrict__ v_,
    const float* __restrict__ wq, const float* __restrict__ wk, const float* __restrict__ wv,
    const float* __restrict__ wo, u16* __restrict__ ws) {
  size_t e = ((size_t)blockIdx.x * 256 + threadIdx.x) * 8;
  const float* src;
  if      (e <  4194304) src = k_ + e;
  else if (e <  8388608) src = q_ + (e - 4194304);
  else if (e < 12582912) src = v_ + (e - 8388608);
  else if (e < 13631488) src = wq + (e - 12582912);
  else if (e < 14680064) src = wk + (e - 13631488);
  else if (e < 15728640) src = wv + (e - 14680064);
  else                   src = wo + (e - 15728640);
  float4 f0 = ((const float4*)src)[0];
  float4 f1 = ((const float4*)src)[1];
  uint4 o;
  o.x = (unsigned)f2bf(f0.x) | ((unsigned)f2bf(f0.y) << 16);
  o.y = (unsigned)f2bf(f0.z) | ((unsigned)f2bf(f0.w) << 16);
  o.z = (unsigned)f2bf(f1.x) | ((unsigned)f2bf(f1.y) << 16);
  o.w = (unsigned)f2bf(f1.z) | ((unsigned)f2bf(f1.w) << 16);
  *(uint4*)(ws + e) = o;
}

// ---------------- GEMM tile v2: BK=64 (half the barriers), chunk-XOR swizzled LDS ----------------
// C = scale * (A[M,K] @ B[N,K]^T), K=1024. BM x 128 tile, 256 threads = 2x2 waves.
// LDS row stride 64 elem (128 B); 16B chunk c stored at c^(row&7) (swizzle applied on the
// GLOBAL address per global_load_lds's linear-LDS requirement). b128 frag reads are 2-way.
template<int BM, bool FINAL>
__device__ __forceinline__ void gemm_tile(const u16* __restrict__ A, const u16* __restrict__ Bm,
                                          u16* __restrict__ Cb, float* __restrict__ Cf,
                                          const float* __restrict__ bias, float scale,
                                          int bm, int bn, int ldc) {
  __shared__ u16 As[BM*64];
  __shared__ u16 Bs[128*64];
  const int tid = threadIdx.x;
  const int wave = tid >> 6, lane = tid & 63;
  const int wm = wave >> 1, wn = wave & 1;
  const int quad = lane >> 4, l16 = lane & 15;
  const int MI = BM / 32;

  f4 acc[MI][4];
  const f4 zz = {0.f, 0.f, 0.f, 0.f};
  #pragma unroll
  for (int i = 0; i < MI; i++)
    #pragma unroll
    for (int j = 0; j < 4; j++) acc[i][j] = zz;

  // staging: thread t covers row kr=t>>3 (+p*32), swizzled chunk cs
  const int kr = tid >> 3;
  const int cs = (tid & 7) ^ (kr & 7);
  const u16* ga = A  + (size_t)(bm*BM  + kr)*1024 + cs*8;
  const u16* gb = Bm + (size_t)(bn*128 + kr)*1024 + cs*8;
  u16* la = As + tid*8;
  u16* lb = Bs + tid*8;

  for (int kt = 0; kt < 1024; kt += 64) {
    #pragma unroll
    for (int p = 0; p < BM/32; p++) ASYNC16(ga + (size_t)(p*32)*1024 + kt, la + p*2048);
    #pragma unroll
    for (int p = 0; p < 4; p++)     ASYNC16(gb + (size_t)(p*32)*1024 + kt, lb + p*2048);
    __syncthreads();               // drains DMA -> tile visible
    #pragma unroll
    for (int kk = 0; kk < 2; kk++) {
      bf8 af[MI];
      #pragma unroll
      for (int mi = 0; mi < MI; mi++)
        af[mi] = *(const bf8*)(As + (wm*(BM/2) + mi*16 + l16)*64 + (((kk*4 + quad) ^ (l16 & 7))*8));
      #pragma unroll
      for (int ni = 0; ni < 4; ni++) {
        bf8 bfr = *(const bf8*)(Bs + (wn*64 + ni*16 + l16)*64 + (((kk*4 + quad) ^ (l16 & 7))*8));
        #pragma unroll
        for (int mi = 0; mi < MI; mi++)
          acc[mi][ni] = __builtin_amdgcn_mfma_f32_16x16x32_bf16(af[mi], bfr, acc[mi][ni], 0, 0, 0);
      }
    }
    __syncthreads();               // all frag reads done before next DMA overwrites
  }

  #pragma unroll
  for (int mi = 0; mi < MI; mi++)
    #pragma unroll
    for (int ni = 0; ni < 4; ni++) {
      const int col = bn*128 + wn*64 + ni*16 + l16;
      #pragma unroll
      for (int r = 0; r < 4; r++) {
        const int row = bm*BM + wm*(BM/2) + mi*16 + quad*4 + r;
        if (FINAL) Cf[(size_t)row*ldc + col] = acc[mi][ni][r] + bias[col];
        else       Cb[(size_t)row*ldc + col] = f2bf(acc[mi][ni][r] * scale);
      }
    }
}

// Q pre-scaled by 0.125*log2(e) so flash_attn uses raw exp2.
#define QSCALE 0.180336880f

// Grid (32,8,3): x = M-tile -> XCD = bm%8, so A-panels are XCD-resident and W streams
// through each XCD's L2 (2 MB < 4 MB). z=2 computes V^T = Wv@xv^T (coalesced transposed out).
__global__ __launch_bounds__(256, 3) void gemm_qkv(
    const u16* __restrict__ xq, const u16* __restrict__ xk, const u16* __restrict__ xv,
    const u16* __restrict__ wq, const u16* __restrict__ wk, const u16* __restrict__ wv,
    u16* __restrict__ Qo, u16* __restrict__ Ko, u16* __restrict__ Vto) {
  if (blockIdx.z == 0)
    gemm_tile<128,false>(xq, wq, Qo, nullptr, nullptr, QSCALE, blockIdx.x, blockIdx.y, 1024);
  else if (blockIdx.z == 1)
    gemm_tile<128,false>(xk, wk, Ko, nullptr, nullptr, 1.0f, blockIdx.x, blockIdx.y, 1024);
  else
    gemm_tile<128,false>(wv, xv, Vto, nullptr, nullptr, 1.0f, blockIdx.y, blockIdx.x, 4096);
}

// Grid (64,8): x = M-tile (64 rows) -> XCD-aligned ctx panels.
__global__ __launch_bounds__(256, 2) void gemm_out(
    const u16* __restrict__ ctx, const u16* __restrict__ wo,
    const float* __restrict__ bias, float* __restrict__ out) {
  gemm_tile<64,true>(ctx, wo, nullptr, out, bias, 1.0f, blockIdx.x, blockIdx.y, 1024);
}

// ---------------- flash attention v9: v7 + phase-shifted K/V staging (split waits) ----------
// Grid (16,32,2): x = h -> XCD = h%8. v6: permuted-key QK^T makes P lane-local. v7: setprio.
// v8 lesson: double-buffer cost 4->2 blocks/CU and LOST (TLP was hiding the drain). v9 keeps
// the single 32KB buffer + 4 blocks/CU but phase-shifts the staging: QK needs only K, PV only
// V. K(t+1) is issued right after K(t) is consumed (its L2 service overlaps PV(t)); V(t+1)
// right after V(t) is consumed (service overlaps QK(t+1)). vmcnt FIFO: at PV-tail outstanding
// = K(t+1)4 + V(t+1)4 -> vmcnt(4) waits exactly K(t+1); at QK-tail outstanding = V(t)4 only.
// 3 barriers/tile. sched_barrier(0) after every asm wait (rule #18).
__global__ __launch_bounds__(256, 4) void flash_attn(
    const u16* __restrict__ Qg, const u16* __restrict__ Kg,
    const u16* __restrict__ Vtg, u16* __restrict__ ctx) {
  __shared__ uint4 smem4[2208];              // 35328 B
  u16* Ks = (u16*)smem4;                     // [0,16384) K [128 key][64 d], 16B-chunk c^=(key&7)
  u16* Vt = (u16*)smem4 + 8192;              // [16384,32768) V^T [64 d][128 key], c^=(d&15)
  float* Of = (float*)smem4;                 // epilogue overlay: 2 x [64][68] f32 = 34816 B
  float* Lf = (float*)smem4 + 2*64*68;       // 128 f32 -> 35328 B total

  const int tid = threadIdx.x;
  const int wave = tid >> 6, lane = tid & 63;
  const int quad = lane >> 4, l16 = lane & 15;
  const int wq = wave >> 1, wk = wave & 1;
  const int h = blockIdx.x, qt = blockIdx.y, b = blockIdx.z;

  // Q B-frags (B[n=qrow=l16][k=dim=quad*8+j]); one-time global load
  bf8 qf[2][2];
  {
    const u16* qp = Qg + (size_t)(b*2048 + qt*64 + wq*32)*1024 + h*64;
    #pragma unroll
    for (int qs = 0; qs < 2; qs++)
      #pragma unroll
      for (int kc = 0; kc < 2; kc++)
        qf[qs][kc] = *(const bf8*)(qp + (size_t)(qs*16 + l16)*1024 + kc*32 + quad*8);
  }

  const f4 zz = {0.f, 0.f, 0.f, 0.f};
  f4 ot[4][2];                 // O^T acc: [d-sub][q-sub], elem (row=d=quad*4+r, col=qrow=l16)
  float lrow[2] = {0.f, 0.f};  // per-lane denominator partial
  #pragma unroll
  for (int ds = 0; ds < 4; ds++)
    #pragma unroll
    for (int qs = 0; qs < 2; qs++) ot[ds][qs] = zz;

  // staging bases (global side carries the XOR chunk-swizzle; LDS side linear)
  const int kr = tid >> 3;
  const u16* kga = Kg + (size_t)(b*2048 + kr)*1024 + h*64 + ((tid & 7) ^ (kr & 7))*8;
  const int vd = tid >> 4;
  const u16* vga = Vtg + (size_t)(h*64 + vd)*4096 + b*2048 + (((tid & 15) ^ vd))*8;
  u16* kld = Ks + tid*8;
  u16* vld = Vt + tid*8;

  // permuted K-row bases for the two QK frags (f=0,1): within a 32-key block,
  // frag f, lane (quad,l16) reads key-row (l16>>2)*8 + f*4 + (l16&3).
  const int prow0 = ((l16 >> 2) << 3) + (l16 & 3);      // f=0
  const int prow1 = prow0 + 4;                           // f=1

  // prologue: issue tile 0 (K first, then V), wait K only
  #pragma unroll
  for (int p = 0; p < 4; p++) ASYNC16(kga + (size_t)(p*32)*1024, kld + p*2048);
  #pragma unroll
  for (int p = 0; p < 4; p++) ASYNC16(vga + (size_t)(p*16)*4096, vld + p*2048);
  asm volatile("s_waitcnt vmcnt(4)" ::: "memory");   // K(0) landed
  __builtin_amdgcn_sched_barrier(0);
  __builtin_amdgcn_s_barrier();                      // K(0) visible

  for (int t = 0; t < 16; t++) {
    // --- QK^T + softmax for both kb halves (reads Ks only) ---
    bf8 pf[2][2];                // [kb][qs] PV B-frags
    #pragma unroll
    for (int kb = 0; kb < 2; kb++) {
      f4 st[2][2];               // [f][qs]: scores for keys quad*8 + f*4 + r
      #pragma unroll
      for (int f = 0; f < 2; f++)
        #pragma unroll
        for (int qs = 0; qs < 2; qs++) st[f][qs] = zz;
      __builtin_amdgcn_s_setprio(1);
      #pragma unroll
      for (int f = 0; f < 2; f++) {
        const int row = wk*64 + kb*32 + (f ? prow1 : prow0);
        #pragma unroll
        for (int kc = 0; kc < 2; kc++) {
          bf8 kf = *(const bf8*)(Ks + row*64 + (((kc*4 + quad) ^ (row & 7))*8));
          #pragma unroll
          for (int qs = 0; qs < 2; qs++)
            st[f][qs] = __builtin_amdgcn_mfma_f32_16x16x32_bf16(kf, qf[qs][kc], st[f][qs], 0, 0, 0);
        }
      }
      __builtin_amdgcn_s_setprio(0);
      #pragma unroll
      for (int qs = 0; qs < 2; qs++) {
        float p0 = fexp2(st[0][qs][0]), p1 = fexp2(st[0][qs][1]);
        float p2 = fexp2(st[0][qs][2]), p3 = fexp2(st[0][qs][3]);
        float p4 = fexp2(st[1][qs][0]), p5 = fexp2(st[1][qs][1]);
        float p6 = fexp2(st[1][qs][2]), p7 = fexp2(st[1][qs][3]);
        lrow[qs] += ((p0 + p1) + (p2 + p3)) + ((p4 + p5) + (p6 + p7));
        union { uint4 u; bf8 v; } pu;
        pu.u.x = pkbf(p0, p1);     // keys quad*8 + 0,1
        pu.u.y = pkbf(p2, p3);     // keys quad*8 + 2,3
        pu.u.z = pkbf(p4, p5);     // keys quad*8 + 4,5
        pu.u.w = pkbf(p6, p7);     // keys quad*8 + 6,7
        pf[kb][qs] = pu.v;
      }
    }
    // K consumed (data-complete) + V(t) landed; then K(t+1) may overwrite Ks
    asm volatile("s_waitcnt vmcnt(0) lgkmcnt(0)" ::: "memory");
    __builtin_amdgcn_sched_barrier(0);
    __builtin_amdgcn_s_barrier();          // bar1: all K reads done, V visible
    if (t < 15) {
      const int kv1 = (t + 1) * 128;
      #pragma unroll
      for (int p = 0; p < 4; p++) ASYNC16(kga + (size_t)(kv1 + p*32)*1024, kld + p*2048);
    }
    // --- O^T += V^T-frag @ P (reads Vt only; K(t+1) DMA in flight to Ks) ---
    __builtin_amdgcn_s_setprio(1);
    #pragma unroll
    for (int kb = 0; kb < 2; kb++)
      #pragma unroll
      for (int ds = 0; ds < 4; ds++) {
        const int d = ds*16 + l16;
        bf8 vf = *(const bf8*)(Vt + d*128 + (((wk*8 + kb*4 + quad) ^ l16)*8));
        #pragma unroll
        for (int qs = 0; qs < 2; qs++)
          ot[ds][qs] = __builtin_amdgcn_mfma_f32_16x16x32_bf16(vf, pf[kb][qs], ot[ds][qs], 0, 0, 0);
      }
    __builtin_amdgcn_s_setprio(0);
    if (t < 15) {
      asm volatile("s_waitcnt lgkmcnt(0)" ::: "memory");  // V reads data-complete
      __builtin_amdgcn_sched_barrier(0);
      __builtin_amdgcn_s_barrier();        // bar2: all V reads done
      const int kv1 = (t + 1) * 128;
      #pragma unroll
      for (int p = 0; p < 4; p++) ASYNC16(vga + (size_t)(p*16)*4096 + kv1, vld + p*2048);
      asm volatile("s_waitcnt vmcnt(4)" ::: "memory");    // K(t+1) landed (FIFO: K before V)
      __builtin_amdgcn_sched_barrier(0);
      __builtin_amdgcn_s_barrier();        // bar3: K(t+1) visible
    }
  }

  // ---------------- epilogue: reduce key-stripes, transpose, normalize, store ----------------
  __syncthreads();                 // everyone done with Ks/Vt -> safe to overlay
  #pragma unroll
  for (int qs = 0; qs < 2; qs++) {
    lrow[qs] += __shfl_xor(lrow[qs], 16);
    lrow[qs] += __shfl_xor(lrow[qs], 32);
  }
  float* Ofw = Of + wk*(64*68);
  #pragma unroll
  for (int ds = 0; ds < 4; ds++)
    #pragma unroll
    for (int qs = 0; qs < 2; qs++)
      #pragma unroll
      for (int r = 0; r < 4; r++)
        Ofw[(wq*32 + qs*16 + l16)*68 + ds*16 + quad*4 + r] = ot[ds][qs][r];
  if (quad == 0) {
    Lf[wk*64 + wq*32 + l16]      = lrow[0];
    Lf[wk*64 + wq*32 + 16 + l16] = lrow[1];
  }
  __syncthreads();
  {
    const int qr = tid >> 2, dp = (tid & 3)*16;
    const float inv = 1.f / (Lf[qr] + Lf[64 + qr]);
    const float* o0 = Of + qr*68 + dp;
    const float* o1 = o0 + 64*68;
    unsigned ow[8];
    #pragma unroll
    for (int i = 0; i < 8; i++)
      ow[i] = pkbf((o0[2*i] + o1[2*i]) * inv, (o0[2*i+1] + o1[2*i+1]) * inv);
    u16* cp = ctx + (size_t)(b*2048 + qt*64 + qr)*1024 + h*64 + dp;
    *(uint4*)cp       = *(uint4*)&ow[0];
    *(uint4*)(cp + 8) = *(uint4*)&ow[4];
  }
}

extern "C" void kernel_launch(void* const* d_in, const int* in_sizes, int n_in,
                              void* d_out, int out_size, void* d_ws, size_t ws_size,
                              hipStream_t stream) {
  const float* key_  = (const float*)d_in[0];
  const float* query = (const float*)d_in[1];
  const float* value = (const float*)d_in[2];
  const float* Wq = (const float*)d_in[3];
  const float* Wk = (const float*)d_in[4];
  const float* Wv = (const float*)d_in[5];
  const float* Wo = (const float*)d_in[6];
  const float* bo = (const float*)d_in[7];
  float* out = (float*)d_out;

  u16* ws  = (u16*)d_ws;                 // needs 67.1 MB of workspace
  u16* xkb = ws;
  u16* xqb = ws + 4194304;
  u16* xvb = ws + 8388608;
  u16* Wqb = ws + 12582912;
  u16* Wkb = ws + 13631488;
  u16* Wvb = ws + 14680064;
  u16* Wob = ws + 15728640;
  u16* Qb  = ws + 16777216;              // Q (pre-scaled by 0.125*log2e) [4096,1024] bf16
  u16* Kb  = ws + 20971520;              // K [4096,1024] bf16
  u16* Vtb = ws + 25165824;              // V^T [1024,4096] bf16
  u16* Cb  = ws + 29360128;              // attention context [4096,1024] bf16

  cvt_all<<<8192, 256, 0, stream>>>(key_, query, value, Wq, Wk, Wv, Wo, ws);
  gemm_qkv<<<dim3(32, 8, 3), 256, 0, stream>>>(xqb, xkb, xvb, Wqb, Wkb, Wvb, Qb, Kb, Vtb);
  flash_attn<<<dim3(16, 32, 2), 256, 0, stream>>>(Qb, Kb, Vtb, Cb);
  gemm_out<<<dim3(64, 8), 256, 0, stream>>>(Cb, Wob, bo, out);
}